// Round 7
// baseline (204.598 us; speedup 1.0000x reference)
//
#include <hip/hip_runtime.h>

#define N_ 32
#define C_ 256
#define G_ 16
#define HW_ 3136          // 56*56
#define HW4_ 784          // HW/4 in vf4 units; 784 = 3*256 + 16
#define EPS_ 1e-12f

typedef float vf4 __attribute__((ext_vector_type(4)));
typedef float vf2 __attribute__((ext_vector_type(2)));

// Integer inputs may arrive as int32 or int64; group_sizes[1]==24 in int32
// layout, ==0 (high word of gs[0]) in int64 LE layout. Values < 2^31 so the
// low word is the value in int64 mode.
__device__ __forceinline__ int rd_int(const int* __restrict__ p, int i, bool is64) {
    return is64 ? p[2 * i] : p[i];
}

__device__ __forceinline__ void acc4(const vf4 v, float& s, float& s2) {
    s += v.x + v.y + v.z + v.w;
    s2 = fmaf(v.x, v.x, s2);
    s2 = fmaf(v.y, v.y, s2);
    s2 = fmaf(v.z, v.z, s2);
    s2 = fmaf(v.w, v.w, s2);
}

__device__ __forceinline__ vf4 aff(const vf4 v, float sc, float sh) {
    vf4 r;
    r.x = fmaf(v.x, sc, sh);
    r.y = fmaf(v.y, sc, sh);
    r.z = fmaf(v.z, sc, sh);
    r.w = fmaf(v.w, sc, sh);
    return r;
}

// ---------------------------------------------------------------------------
// v7: move the permutation OFF the bulk path. Exonerated so far (all ~73 us
// kernel-sum): NT-vs-plain stores (R6 null), occupancy 16->32 waves/CU,
// rolled vs reg-batched loads. Never varied until now: the 103 MB read is a
// gather of PERMUTED 12.5 KB rows, and k2 runs a per-block stats prologue.
//
// The permutation is row relabeling only, so apply it to the 64 KB rsums
// array, not the 103 MB x array:
//   k1   : natural-order rows, pure sequential read  -> rsums[src_row]
//   kmid : 512 tiny blocks, gather rsums via indexes, group stats,
//          scatter per-row scale/shift indexed by SOURCE row (~128 KB total)
//   k2   : natural-order rows, pure sequential read+write; prologue is two
//          uniform scalar loads. No indexes/scan/shuffle/LDS/sync anywhere
//          in the bulk kernels.
// out[src] = f(x[src]) with per-permuted-row stats == reference's
// gather -> normalize -> inverse-scatter chain.
// ---------------------------------------------------------------------------

// Kernel 1: per natural row pair: S / S2 -> rsums[row*2 + {0,1}]
__global__ __launch_bounds__(256, 8) void vgn_reduce(
    const float* __restrict__ x,
    float*       __restrict__ rsums)
{
    const int t  = threadIdx.x;
    const int r0 = blockIdx.x * 2;

    const vf4* p0 = (const vf4*)x + (size_t)r0 * HW4_;
    const vf4* p1 = p0 + HW4_;

    vf4 a0 = p0[t], b0 = p0[t + 256], c0 = p0[t + 512];
    vf4 a1 = p1[t], b1 = p1[t + 256], c1 = p1[t + 512];

    float sA = 0.f, qA = 0.f, sB = 0.f, qB = 0.f;
    if (t < 16) {                       // 784 = 3*256 + 16 tail
        vf4 d0 = p0[768 + t];
        vf4 d1 = p1[768 + t];
        acc4(d0, sA, qA);
        acc4(d1, sB, qB);
    }
    acc4(a0, sA, qA); acc4(b0, sA, qA); acc4(c0, sA, qA);
    acc4(a1, sB, qB); acc4(b1, sB, qB); acc4(c1, sB, qB);

    #pragma unroll
    for (int off = 32; off > 0; off >>= 1) {
        sA += __shfl_down(sA, off);
        qA += __shfl_down(qA, off);
        sB += __shfl_down(sB, off);
        qB += __shfl_down(qB, off);
    }

    __shared__ float red[4][4];         // [wave][val]
    if ((t & 63) == 0) {
        const int w = t >> 6;
        red[w][0] = sA; red[w][1] = qA; red[w][2] = sB; red[w][3] = qB;
    }
    __syncthreads();
    if (t < 4)                          // {S,S2} row0, {S,S2} row1
        rsums[r0 * 2 + t] = red[0][t] + red[1][t] + red[2][t] + red[3][t];
}

// Middle kernel: one 64-thread block per (n, group). Gathers the group's
// per-row partials through indexes (64 KB array, cache-resident), computes
// mu / ivar, scatters per-row scale/shift INDEXED BY SOURCE ROW so k2 needs
// no permutation at all.
__global__ __launch_bounds__(64) void vgn_stats(
    const int*   __restrict__ indexes,
    const int*   __restrict__ group_sizes,
    const float* __restrict__ weight,
    const float* __restrict__ bias,
    const float* __restrict__ rsums,
    float*       __restrict__ scaleS,
    float*       __restrict__ shiftS)
{
    const bool is64 = (group_sizes[1] == 0);
    const int n = blockIdx.x >> 4;      // G_ == 16
    const int g = blockIdx.x & (G_ - 1);
    const int l = threadIdx.x;          // 0..63

    int Pg = 0;
    for (int k = 0; k < g; k++) Pg += rd_int(group_sizes, k, is64);
    const int gsz = rd_int(group_sizes, g, is64);

    int src = 0;
    float a = 0.f, b = 0.f;
    if (l < gsz) {
        src = rd_int(indexes, n * C_ + Pg + l, is64);   // global source row
        const vf2 pr = ((const vf2*)rsums)[src];
        a = pr.x; b = pr.y;
    }
    float A = a, B = b;
    #pragma unroll
    for (int off = 32; off > 0; off >>= 1) {
        A += __shfl_down(A, off);
        B += __shfl_down(B, off);
    }
    A = __shfl(A, 0);
    B = __shfl(B, 0);

    if (l < gsz) {
        const float cnt = (float)gsz * (float)HW_;
        const float mu  = A / cnt;
        const float var = (B - mu * A) / (cnt - 1.0f);  // ddof=1, matches ref
        const float ivr = rsqrtf(var + EPS_);
        const int   c   = Pg + l;                       // channel of this row
        const float sc  = ivr * weight[c];
        scaleS[src] = sc;
        shiftS[src] = fmaf(-mu, sc, bias[c]);
    }
}

// Kernel 2: per natural row pair: pure stream. Two uniform scalar loads for
// the row's scale/shift, then sequential read + write.
__global__ __launch_bounds__(256, 8) void vgn_norm(
    const float* __restrict__ x,
    const float* __restrict__ scaleS,
    const float* __restrict__ shiftS,
    float*       __restrict__ out)
{
    const int t  = threadIdx.x;
    const int r0 = blockIdx.x * 2;

    const vf4* p0 = (const vf4*)x + (size_t)r0 * HW4_;
    const vf4* p1 = p0 + HW4_;
    vf4* o0 = (vf4*)out + (size_t)r0 * HW4_;
    vf4* o1 = o0 + HW4_;

    // issue the streaming loads first; scalar scale/shift loads ride along
    vf4 a0 = p0[t], b0 = p0[t + 256], c0 = p0[t + 512];
    vf4 a1 = p1[t], b1 = p1[t + 256], c1 = p1[t + 512];
    vf4 d0, d1;
    const bool tail = (t < 16);
    if (tail) { d0 = p0[768 + t]; d1 = p1[768 + t]; }

    const float sc0 = scaleS[r0],     sh0 = shiftS[r0];
    const float sc1 = scaleS[r0 + 1], sh1 = shiftS[r0 + 1];

    o0[t]       = aff(a0, sc0, sh0);
    o0[t + 256] = aff(b0, sc0, sh0);
    o0[t + 512] = aff(c0, sc0, sh0);
    o1[t]       = aff(a1, sc1, sh1);
    o1[t + 256] = aff(b1, sc1, sh1);
    o1[t + 512] = aff(c1, sc1, sh1);
    if (tail) {
        o0[768 + t] = aff(d0, sc0, sh0);
        o1[768 + t] = aff(d1, sc1, sh1);
    }
}

// ---------------------------------------------------------------------------
extern "C" void kernel_launch(void* const* d_in, const int* in_sizes, int n_in,
                              void* d_out, int out_size, void* d_ws, size_t ws_size,
                              hipStream_t stream) {
    const float* x           = (const float*)d_in[0];
    const float* weight      = (const float*)d_in[1];
    const float* bias        = (const float*)d_in[2];
    const int*   group_sizes = (const int*)  d_in[3];
    const int*   indexes     = (const int*)  d_in[4];
    // d_in[5] = reverse_indexes (unused: permutation handled via indexes on
    // the tiny rsums array; bulk kernels are permutation-free)

    float* rsums  = (float*)d_ws;                    // 8192 vf2  = 64 KB
    float* scaleS = (float*)d_ws + 2 * N_ * C_;      // 8192 f32  = 32 KB
    float* shiftS = scaleS + N_ * C_;                // 8192 f32  = 32 KB
    float* outp   = (float*)d_out;

    dim3 blkBulk(256), gridBulk(N_ * C_ / 2);        // 4096 blocks
    vgn_reduce<<<gridBulk, blkBulk, 0, stream>>>(x, rsums);
    vgn_stats <<<dim3(N_ * G_), dim3(64), 0, stream>>>(indexes, group_sizes,
                                                       weight, bias, rsums,
                                                       scaleS, shiftS);
    vgn_norm  <<<gridBulk, blkBulk, 0, stream>>>(x, scaleS, shiftS, outp);
}